// Round 10
// baseline (759.309 us; speedup 1.0000x reference)
//
#include <hip/hip_runtime.h>
#include <math.h>

// Problem constants
#define B_   32
#define L_   128
#define W_   16
#define CE_  64     // char embed
#define NF_  128    // num filters
#define WE_  256    // word embed
#define E_   384    // NF_ + WE_
#define H_   512
#define G4_  2048   // 4*H
#define O1_  512
#define NC_  17
#define LSTM_BLOCKS 64          // 32 per direction
#define AGENT_SC __HIP_MEMORY_SCOPE_AGENT

typedef __attribute__((ext_vector_type(4))) float f32x4;
typedef _Float16 half8 __attribute__((ext_vector_type(8)));
typedef _Float16 half4 __attribute__((ext_vector_type(4)));

__device__ inline half8 cvt8(float4 a, float4 b) {
    half8 r;
    r[0] = (_Float16)a.x; r[1] = (_Float16)a.y;
    r[2] = (_Float16)a.z; r[3] = (_Float16)a.w;
    r[4] = (_Float16)b.x; r[5] = (_Float16)b.y;
    r[6] = (_Float16)b.z; r[7] = (_Float16)b.w;
    return r;
}

// sc1 (agent-coherent, MALL-direct) loads via inline asm
__device__ inline unsigned int ld_u32_sc1(const unsigned int* p) {
    unsigned int v;
    asm volatile("global_load_dword %0, %1, off sc1\n\ts_waitcnt vmcnt(0)"
                 : "=v"(v) : "v"(p) : "memory");
    return v;
}
__device__ inline half8 ld_b128_sc1(const void* p) {
    half8 v;
    asm volatile("global_load_dwordx4 %0, %1, off sc1"
                 : "=v"(v) : "v"(p) : "memory");
    return v;
}

__device__ inline float sigm_f(float x) { return 1.f / (1.f + __expf(-x)); }
__device__ inline float tanh_f(float x) { return 2.f / (1.f + __expf(-2.f * x)) - 1.f; }

// ---------------------------------------------------------------------------
// Kernel 0: prep — convert w_ih_f / w_ih_b / w1 to fp16, transpose conv
// weights, zero the lstm flags.  550912 jobs, grid 2152 x 256 exact.
// ---------------------------------------------------------------------------
__global__ __launch_bounds__(256) void prep_k(
    const float* __restrict__ wf, const float* __restrict__ wb,
    const float* __restrict__ w1, const float* __restrict__ cw,
    _Float16* __restrict__ w16, float* __restrict__ cwT,
    unsigned int* __restrict__ flags)
{
    int i = blockIdx.x * 256 + threadIdx.x;
    if (i < 524288) {
        const float* src; _Float16* dst; int j;
        if (i < 196608)      { src = wf; dst = w16;           j = i; }
        else if (i < 393216) { src = wb; dst = w16 + 786432;  j = i - 196608; }
        else                 { src = w1; dst = w16 + 1572864; j = i - 393216; }
        float4 v = ((const float4*)src)[j];
        half4 h;
        h[0] = (_Float16)v.x; h[1] = (_Float16)v.y;
        h[2] = (_Float16)v.z; h[3] = (_Float16)v.w;
        ((half4*)dst)[j] = h;
    } else if (i < 548864) {
        int t = i - 524288;                 // conv transpose, 24576 jobs
        int f = t / 192;
        int rem = t - f * 192;
        int c = rem / 3;
        int k = rem - c * 3;
        cwT[(c * 3 + k) * NF_ + f] = cw[t];
    } else {                                // 2048 flag words
        flags[i - 548864] = 0;
    }
}

// ---------------------------------------------------------------------------
// Kernel 1: char embed gather + conv1d(k=3,pad=1) + relu + maxpool + word
// embed concat -> x_h TIME-MAJOR [l*32+b][384] fp16
// ---------------------------------------------------------------------------
__global__ __launch_bounds__(64) void embed_cnn(
    const int* __restrict__ word_ids, const int* __restrict__ char_ids,
    const float* __restrict__ char_emb, const float* __restrict__ word_emb,
    const float* __restrict__ cwT, const float* __restrict__ conv_b,
    _Float16* __restrict__ x_h)
{
    __shared__ float ce[CE_][20];
    __shared__ int ids[W_];
    int bl = blockIdx.x;                    // b*128 + l
    int tid = threadIdx.x;
    int orow = ((bl & 127) << 5) | (bl >> 7);   // l*32 + b (time-major)

    if (tid < W_) ids[tid] = char_ids[bl * W_ + tid];
    ce[tid][0] = 0.f;
    ce[tid][17] = 0.f;
    __syncthreads();

    for (int i = tid; i < W_ * CE_; i += 64) {
        int w = i >> 6, c = i & 63;
        ce[c][w + 1] = char_emb[ids[w] * CE_ + c];
    }
    __syncthreads();

    int f0 = tid, f1 = tid + 64;
    float acc0[W_], acc1[W_];
#pragma unroll
    for (int w = 0; w < W_; w++) { acc0[w] = 0.f; acc1[w] = 0.f; }

    for (int c = 0; c < CE_; c++) {
        float win[18];
        float4 v0 = *(const float4*)&ce[c][0];
        float4 v1 = *(const float4*)&ce[c][4];
        float4 v2 = *(const float4*)&ce[c][8];
        float4 v3 = *(const float4*)&ce[c][12];
        win[0]=v0.x; win[1]=v0.y; win[2]=v0.z; win[3]=v0.w;
        win[4]=v1.x; win[5]=v1.y; win[6]=v1.z; win[7]=v1.w;
        win[8]=v2.x; win[9]=v2.y; win[10]=v2.z; win[11]=v2.w;
        win[12]=v3.x; win[13]=v3.y; win[14]=v3.z; win[15]=v3.w;
        win[16] = ce[c][16];
        win[17] = ce[c][17];
        const float* wp = cwT + c * 3 * NF_;
        float k00 = wp[f0], k01 = wp[NF_ + f0], k02 = wp[2 * NF_ + f0];
        float k10 = wp[f1], k11 = wp[NF_ + f1], k12 = wp[2 * NF_ + f1];
#pragma unroll
        for (int w = 0; w < W_; w++) {
            acc0[w] += win[w] * k00 + win[w + 1] * k01 + win[w + 2] * k02;
            acc1[w] += win[w] * k10 + win[w + 1] * k11 + win[w + 2] * k12;
        }
    }
    float m0 = acc0[0], m1 = acc1[0];
#pragma unroll
    for (int w = 1; w < W_; w++) { m0 = fmaxf(m0, acc0[w]); m1 = fmaxf(m1, acc1[w]); }
    m0 = fmaxf(0.f, m0 + conv_b[f0]);
    m1 = fmaxf(0.f, m1 + conv_b[f1]);
    x_h[orow * E_ + f0] = (_Float16)m0;
    x_h[orow * E_ + f1] = (_Float16)m1;

    int wid = word_ids[bl];
    float4 wv = *(const float4*)&word_emb[wid * WE_ + tid * 4];
    half4 h;
    h[0] = (_Float16)wv.x; h[1] = (_Float16)wv.y;
    h[2] = (_Float16)wv.z; h[3] = (_Float16)wv.w;
    *(half4*)&x_h[orow * E_ + NF_ + tid * 4] = h;
}

// ---------------------------------------------------------------------------
// 128x128 fp16 MFMA GEMM (m97-style): global_load_lds width-16 staging,
// linear LDS [row][32k], 4 waves in 2x2, 16 MFMA per K-step.
// C = A[M,K] @ W[N,K]^T + bias (f32 out).
// mode 0: C[m][n]; 1: m already time-major (identity); 2: reversed time.
// ---------------------------------------------------------------------------
__device__ __forceinline__ void gemm128_body(
    const _Float16* A, const _Float16* Wt, const float* bias, float* C,
    int bm, int bn, int N, int K, int mode, int act)
{
    __shared__ _Float16 As[128 * 32];
    __shared__ _Float16 Bs[128 * 32];
    int tid = threadIdx.x;
    int wid = tid >> 6, lane = tid & 63;
    int lr = lane & 15, lk = lane >> 4;
    int wr = wid >> 1, wc = wid & 1;

    f32x4 acc[4][4];
#pragma unroll
    for (int mi = 0; mi < 4; mi++)
#pragma unroll
        for (int ni = 0; ni < 4; ni++)
            acc[mi][ni] = (f32x4){0.f, 0.f, 0.f, 0.f};

    int srow = wid * 32 + (lane >> 2);      // staging row (+16 for inst 1)
    int kb   = (lane & 3) * 16;             // byte within row's 64B

    for (int kt = 0; kt < K; kt += 32) {
        const char* Ab = (const char*)A + ((size_t)bm * K + kt) * 2;
        const char* Bb = (const char*)Wt + ((size_t)bn * K + kt) * 2;
#pragma unroll
        for (int inst = 0; inst < 2; inst++) {
            int row = srow + inst * 16;
            int lb  = wid * 2048 + inst * 1024;
            __builtin_amdgcn_global_load_lds(
                (const __attribute__((address_space(1))) void*)(Ab + (size_t)row * (K * 2) + kb),
                (__attribute__((address_space(3))) void*)((char*)As + lb), 16, 0, 0);
            __builtin_amdgcn_global_load_lds(
                (const __attribute__((address_space(1))) void*)(Bb + (size_t)row * (K * 2) + kb),
                (__attribute__((address_space(3))) void*)((char*)Bs + lb), 16, 0, 0);
        }
        __syncthreads();

        half8 af[4], bf[4];
#pragma unroll
        for (int mi = 0; mi < 4; mi++)
            af[mi] = *(const half8*)((const char*)As + (wr * 64 + mi * 16 + lr) * 64 + lk * 16);
#pragma unroll
        for (int ni = 0; ni < 4; ni++)
            bf[ni] = *(const half8*)((const char*)Bs + (wc * 64 + ni * 16 + lr) * 64 + lk * 16);
#pragma unroll
        for (int mi = 0; mi < 4; mi++)
#pragma unroll
            for (int ni = 0; ni < 4; ni++)
                acc[mi][ni] = __builtin_amdgcn_mfma_f32_16x16x32_f16(
                                  af[mi], bf[ni], acc[mi][ni], 0, 0, 0);
        __syncthreads();
    }

#pragma unroll
    for (int ni = 0; ni < 4; ni++) {
        int n = bn + wc * 64 + ni * 16 + lr;
        float bv = bias[n];
#pragma unroll
        for (int mi = 0; mi < 4; mi++) {
#pragma unroll
            for (int r = 0; r < 4; r++) {
                int m = bm + wr * 64 + mi * 16 + lk * 4 + r;
                int orow = m;
                if (mode == 2) orow = ((127 - (m >> 5)) << 5) | (m & 31);
                float v = acc[mi][ni][r] + bv;
                if (act) v = v > 0.f ? v : expm1f(v);
                C[(size_t)orow * N + n] = v;
            }
        }
    }
}

// Fused dual-direction input projection: grid (32, 16, 2)
__global__ __launch_bounds__(256) void gemm128_proj(
    const _Float16* __restrict__ x16, const _Float16* __restrict__ w16,
    const float* __restrict__ bf, const float* __restrict__ bb,
    float* __restrict__ gxf, float* __restrict__ gxb)
{
    int dir = blockIdx.z;
    gemm128_body(x16, w16 + (size_t)dir * 786432, dir ? bb : bf,
                 dir ? gxb : gxf, blockIdx.x * 128, blockIdx.y * 128,
                 G4_, E_, 1 + dir, 0);
}

// head1: z = ELU(hcat16 @ w1^T + b1), grid (32, 4)
__global__ __launch_bounds__(256) void gemm128_head(
    const _Float16* __restrict__ hcat16, const _Float16* __restrict__ w116,
    const float* __restrict__ b1, float* __restrict__ z)
{
    gemm128_body(hcat16, w116, b1, z, blockIdx.x * 128, blockIdx.y * 128,
                 O1_, 2 * H_, 0, 1);
}

// ---------------------------------------------------------------------------
// Kernel 2b: small fp32 GEMM for head2 (N=17)
// ---------------------------------------------------------------------------
__global__ __launch_bounds__(256) void gemm_bias_act(
    const float* __restrict__ A, const float* __restrict__ Wt,
    const float* __restrict__ bias, float* __restrict__ C,
    int M, int N, int K)
{
    __shared__ float As[16][68];
    __shared__ float Bs[16][68];
    int tid = threadIdx.x;
    int bm = blockIdx.x * 64;
    int bn = blockIdx.y * 64;
    int tx = tid & 15, ty = tid >> 4;
    int r = tid >> 2, kq = (tid & 3) << 2;
    float acc[4][4] = {};

    for (int kt = 0; kt < K; kt += 16) {
        float4 av = *(const float4*)&A[(bm + r) * K + kt + kq];
        As[kq + 0][r] = av.x; As[kq + 1][r] = av.y;
        As[kq + 2][r] = av.z; As[kq + 3][r] = av.w;
        int n = bn + r;
        float4 wv = make_float4(0.f, 0.f, 0.f, 0.f);
        if (n < N) wv = *(const float4*)&Wt[n * K + kt + kq];
        Bs[kq + 0][r] = wv.x; Bs[kq + 1][r] = wv.y;
        Bs[kq + 2][r] = wv.z; Bs[kq + 3][r] = wv.w;
        __syncthreads();
#pragma unroll
        for (int k = 0; k < 16; k++) {
            float4 a = *(const float4*)&As[k][ty << 2];
            float4 b = *(const float4*)&Bs[k][tx << 2];
            acc[0][0] += a.x * b.x; acc[0][1] += a.x * b.y;
            acc[0][2] += a.x * b.z; acc[0][3] += a.x * b.w;
            acc[1][0] += a.y * b.x; acc[1][1] += a.y * b.y;
            acc[1][2] += a.y * b.z; acc[1][3] += a.y * b.w;
            acc[2][0] += a.z * b.x; acc[2][1] += a.z * b.y;
            acc[2][2] += a.z * b.z; acc[2][3] += a.z * b.w;
            acc[3][0] += a.w * b.x; acc[3][1] += a.w * b.y;
            acc[3][2] += a.w * b.z; acc[3][3] += a.w * b.w;
        }
        __syncthreads();
    }

#pragma unroll
    for (int ii = 0; ii < 4; ii++) {
        int m = bm + (ty << 2) + ii;
#pragma unroll
        for (int jj = 0; jj < 4; jj++) {
            int n = bn + (tx << 2) + jj;
            if (n < N) C[m * N + n] = acc[ii][jj] + bias[n];
        }
    }
}

// ---------------------------------------------------------------------------
// Kernel 3: persistent MFMA BLSTM, in-wave gates.
// Wave w owns units U0+4w..U0+4w+3, ALL 4 gates (A-rows ordered [unit][gate]).
// D-frag: lane(lr,lk) -> batch lr (d0) / lr+16 (d1), unit U0+4w+lk,
// d[r] = gate r  ->  cell update fully in-register, no gate exchange.
// t=0 skips stage+MFMA (h0=0) -> no hbuf memset needed.
// ---------------------------------------------------------------------------
__global__ __launch_bounds__(256) void lstm_mfma5(
    const float* __restrict__ gxf, const float* __restrict__ gxb,
    const float* __restrict__ whh_f, const float* __restrict__ whh_b,
    unsigned int* __restrict__ hbuf,         // [2 buf][2 dir][32][256] u32
    _Float16* __restrict__ hcat_h,           // [4096][1024] fp16
    unsigned int* __restrict__ flags)        // [64 * 32] (128B per block)
{
    __shared__ unsigned int hlds[8192];      // 32 KB swizzled h

    int bx = blockIdx.x;
    int dir = bx >> 5;
    int U0 = (bx & 31) * 16;
    int tid = threadIdx.x;
    int wid = tid >> 6;
    int lane = tid & 63;
    int lr = lane & 15, lk = lane >> 4;

    const float* gx = dir ? gxb : gxf;

    // A-fragments: row lr -> unit U0+4*wid+(lr>>2), gate lr&3  (f32 -> f16)
    half8 afrag[16];
    {
        int ua = U0 + wid * 4 + (lr >> 2);
        int gg = lr & 3;
        const float* wrow = (dir ? whh_b : whh_f)
                          + (size_t)(gg * H_ + ua) * H_ + lk * 8;
#pragma unroll
        for (int ks = 0; ks < 16; ks++) {
            float4 a = *(const float4*)(wrow + ks * 32);
            float4 b = *(const float4*)(wrow + ks * 32 + 4);
            afrag[ks] = cvt8(a, b);
        }
    }

    int b0 = lr, b1 = lr + 16;
    int u = U0 + wid * 4 + lk;          // this lane's unit in the update
    float c0 = 0.f, c1 = 0.f;
    const unsigned int* dflags = flags + dir * 32 * 32;

    for (int t = 0; t < L_; t++) {
        // ---- gx prefetch (independent of h; hides under poll/stage waits)
        float gxv0[4], gxv1[4];
        {
            const float* gxt = gx + (size_t)t * B_ * G4_;
#pragma unroll
            for (int gg = 0; gg < 4; gg++) {
                gxv0[gg] = gxt[b0 * G4_ + gg * H_ + u];
                gxv1[gg] = gxt[b1 * G4_ + gg * H_ + u];
            }
        }

        f32x4 d0 = {0.f, 0.f, 0.f, 0.f};
        f32x4 d1 = {0.f, 0.f, 0.f, 0.f};
        if (t > 0) {
            // ---- wait for peers' h_{t-1}: 32 padded flags, one per lane
            unsigned tgt = (unsigned)t;
            const unsigned int* fp = dflags + (tid & 31) * 32;
            while (ld_u32_sc1(fp) < tgt)
                __builtin_amdgcn_s_sleep(1);
            __builtin_amdgcn_sched_barrier(0);

            // ---- stage h_{t-1} into swizzled LDS: 8 x dwordx4 sc1
            {
                const char* hsrc = (const char*)(hbuf
                                 + ((((t + 1) & 1) * 2 + dir) * (32 * 256)));
                half8 tmp[8];
#pragma unroll
                for (int p = 0; p < 8; p++)
                    tmp[p] = ld_b128_sc1(hsrc + p * 4096 + tid * 16);
                asm volatile("s_waitcnt vmcnt(0)" ::: "memory");
                __builtin_amdgcn_sched_barrier(0);
#pragma unroll
                for (int p = 0; p < 8; p++) {
                    int o = p * 4096 + tid * 16;
                    int row = o >> 10;
                    *(half8*)((char*)hlds + (o ^ ((row & 7) << 4))) = tmp[p];
                }
            }
            __syncthreads();   // hlds ready

            // ---- MFMA: all 4 gates of this wave's 4 units, 32 batches
            const char* hb = (const char*)hlds;
            int base0 = lr * 1024 + lk * 16;
            int base1 = (16 + lr) * 1024 + lk * 16;
            int sw = (lr & 7) << 4;
#pragma unroll
            for (int ks = 0; ks < 16; ks++) {
                half8 f0 = *(const half8*)(hb + ((base0 + ks * 64) ^ sw));
                half8 f1 = *(const half8*)(hb + ((base1 + ks * 64) ^ sw));
                d0 = __builtin_amdgcn_mfma_f32_16x16x32_f16(afrag[ks], f0, d0, 0, 0, 0);
                d1 = __builtin_amdgcn_mfma_f32_16x16x32_f16(afrag[ks], f1, d1, 0, 0, 0);
            }
        }

        // ---- in-register cell update (all 256 threads)
        {
            float i0 = sigm_f(d0[0] + gxv0[0]);
            float f0_ = sigm_f(d0[1] + gxv0[1]);
            float g0 = tanh_f(d0[2] + gxv0[2]);
            float o0 = sigm_f(d0[3] + gxv0[3]);
            c0 = f0_ * c0 + i0 * g0;
            float h0 = o0 * tanh_f(c0);

            float i1 = sigm_f(d1[0] + gxv1[0]);
            float f1_ = sigm_f(d1[1] + gxv1[1]);
            float g1 = tanh_f(d1[2] + gxv1[2]);
            float o1 = sigm_f(d1[3] + gxv1[3]);
            c1 = f1_ * c1 + i1 * g1;
            float h1 = o1 * tanh_f(c1);

            // pack (u, u+1) pairs: partner lane lk^1 = lane^16
            float h0n = __shfl_xor(h0, 16);
            float h1n = __shfl_xor(h1, 16);
            int ll = dir ? (L_ - 1 - t) : t;
            if ((lk & 1) == 0) {
                union { _Float16 h[2]; unsigned v; } p0, p1;
                p0.h[0] = (_Float16)h0; p0.h[1] = (_Float16)h0n;
                p1.h[0] = (_Float16)h1; p1.h[1] = (_Float16)h1n;
                unsigned int* hdst = hbuf + (((t & 1) * 2 + dir) * (32 * 256));
                int wj = u >> 1;
                __hip_atomic_store(&hdst[b0 * 256 + wj], p0.v,
                                   __ATOMIC_RELAXED, AGENT_SC);
                __hip_atomic_store(&hdst[b1 * 256 + wj], p1.v,
                                   __ATOMIC_RELAXED, AGENT_SC);
                *(unsigned int*)((char*)hcat_h
                    + ((size_t)(b0 * L_ + ll)) * 2048 + dir * 1024 + u * 2) = p0.v;
                *(unsigned int*)((char*)hcat_h
                    + ((size_t)(b1 * L_ + ll)) * 2048 + dir * 1024 + u * 2) = p1.v;
            }
        }

        // ---- arrive: syncthreads drains vmcnt(0) -> all h stores at MALL
        __syncthreads();
        if (tid == 0)
            __hip_atomic_store(flags + bx * 32, (unsigned)(t + 1),
                               __ATOMIC_RELAXED, AGENT_SC);
    }
}

// ---------------------------------------------------------------------------
// Launch
// ---------------------------------------------------------------------------
extern "C" void kernel_launch(void* const* d_in, const int* in_sizes, int n_in,
                              void* d_out, int out_size, void* d_ws, size_t ws_size,
                              hipStream_t stream)
{
    const int*   word_ids = (const int*)d_in[0];
    const int*   char_ids = (const int*)d_in[1];
    const float* char_emb = (const float*)d_in[3];
    const float* word_emb = (const float*)d_in[4];
    const float* conv_w   = (const float*)d_in[5];
    const float* conv_b   = (const float*)d_in[6];
    const float* w_ih_f   = (const float*)d_in[7];
    const float* w_hh_f   = (const float*)d_in[8];
    const float* b_f      = (const float*)d_in[9];
    const float* w_ih_b   = (const float*)d_in[10];
    const float* w_hh_b   = (const float*)d_in[11];
    const float* b_b      = (const float*)d_in[12];
    const float* w1       = (const float*)d_in[13];
    const float* b1       = (const float*)d_in[14];
    const float* w2       = (const float*)d_in[15];
    const float* b2       = (const float*)d_in[16];
    float* out = (float*)d_out;
    float* ws  = (float*)d_ws;

    // workspace layout (f32 offsets), ~91.6 MB
    _Float16* x_h   = (_Float16*)(ws + 0);            // [4096][384] fp16, time-major
    float* gxf  = ws + 786432;       // [128*32][2048] f32
    float* gxb  = ws + 9175040;      // [128*32][2048] f32 (reversed time)
    _Float16* hcat_h = (_Float16*)(ws + 17563648);    // [4096][1024] fp16
    float* z    = ws + 19660800;     // [4096][512] f32
    unsigned int* hbuf = (unsigned int*)(ws + 21757952);  // [2][2][32][256] u32
    float* cwT  = ws + 21823488;     // [64][3][128]
    _Float16* w16 = (_Float16*)(ws + 21848064);       // wf16|wb16|w116 (2.1M fp16)
    unsigned int* flags = (unsigned int*)(ws + 22896640); // [64*32] padded

    prep_k<<<2152, 256, 0, stream>>>(w_ih_f, w_ih_b, w1, conv_w, w16, cwT, flags);
    embed_cnn<<<4096, 64, 0, stream>>>(word_ids, char_ids, char_emb, word_emb,
                                       cwT, conv_b, x_h);

    // fused input projections -> gxf/gxb (time-major f32)
    dim3 gp(32, 16, 2);
    gemm128_proj<<<gp, 256, 0, stream>>>(x_h, w16, b_f, b_b, gxf, gxb);

    {
        const float* a0 = gxf; const float* a1 = gxb;
        const float* a2 = w_hh_f; const float* a3 = w_hh_b;
        unsigned int* a4 = hbuf;
        _Float16* a5 = hcat_h;
        unsigned int* a6 = flags;
        void* args[] = { &a0, &a1, &a2, &a3, &a4, &a5, &a6 };
        hipLaunchCooperativeKernel((void*)lstm_mfma5, dim3(LSTM_BLOCKS), dim3(256),
                                   args, 0, stream);
    }

    // head1: z = ELU(hcat @ w1^T + b1)
    dim3 g2(32, 4);
    gemm128_head<<<g2, 256, 0, stream>>>(hcat_h, w16 + 1572864, b1, z);
    // head2: out = z @ w2^T + b2 (small fp32)
    dim3 g3(64, 1);
    gemm_bias_act<<<g3, 256, 0, stream>>>(z, w2, b2, out, 4096, NC_, O1_);
}